// Round 5
// baseline (350.141 us; speedup 1.0000x reference)
//
#include <hip/hip_runtime.h>

#define D_IN   256
#define HID    256
#define NNODES 100000
#define NEDGE  262144

typedef short short8            __attribute__((ext_vector_type(8)));
typedef float float4v           __attribute__((ext_vector_type(4)));
typedef unsigned short ushort8  __attribute__((ext_vector_type(8)));

__device__ __forceinline__ unsigned short f32_to_bf16_rne(float f) {
    unsigned int u = __float_as_uint(f);
    unsigned int r = u + 0x7FFFu + ((u >> 16) & 1u);
    return (unsigned short)(r >> 16);
}
__device__ __forceinline__ float bf16_to_f32(unsigned short h) {
    return __uint_as_float(((unsigned int)h) << 16);
}

// -------- W1 (fp32 [2*256][256], k-major) -> Wt (bf16 [z][n][k]) — LDS tile transpose --------
__global__ __launch_bounds__(256) void convert_w(
    const float* __restrict__ W1, unsigned short* __restrict__ Wt)
{
    __shared__ float tile[64][65];
    const int z = blockIdx.z, kb = blockIdx.x * 64, nb = blockIdx.y * 64;
    const int t = threadIdx.x;
    const int g = t >> 6, c = t & 63;
#pragma unroll
    for (int r = 0; r < 16; r++) {
        int kl = g * 16 + r;
        tile[kl][c] = W1[((size_t)(z * 256 + kb + kl)) * 256 + nb + c];
    }
    __syncthreads();
#pragma unroll
    for (int r = 0; r < 16; r++) {
        int nl = g * 16 + r;
        Wt[((size_t)(z * 256 + nb + nl)) * 256 + kb + c] = f32_to_bf16_rne(tile[c][nl]);
    }
}

// -------- Phase 1: U = Xsrc@W1_top + b1 (bf16), V = Xdst@W1_bot (bf16) --------
// 64(M) x 256(N) tile (N full: A fetched once), 512 thr = 8 waves (2m x 4n),
// wave tile 32x64 -> acc[2][4] = 32 AGPR, BK=64, 16x16x32 bf16 MFMA.
// LDS 45 KB; __launch_bounds__(512,4) targets 2 blocks/CU (16 waves) so one
// block's MFMA covers the other's staging/barrier latency.
// NOTE: register-prefetch across the MFMA section spills (round-3: +86MB scratch
// writes) — do not extend staging live ranges across MFMA.
#define SA 72      // padded k-stride (ushorts): 144 B = 16B-mult, 2-way bank alias (free)

__global__ __launch_bounds__(512, 4) void gemm_xw_mfma(
    const float* __restrict__ Xsrc, const float* __restrict__ Xdst,
    const unsigned short* __restrict__ Wt, const float* __restrict__ b1,
    unsigned short* __restrict__ U, unsigned short* __restrict__ V)
{
    const int zz = blockIdx.z;
    const float* X = zz ? Xdst : Xsrc;
    const unsigned short* Wz = Wt + (size_t)zz * 256 * 256;
    unsigned short* C = zz ? V : U;

    const int m0 = blockIdx.x * 64;

    __shared__ __align__(16) unsigned short smem[23040];   // 45 KB
    unsigned short* As = smem;          // [64][SA]
    unsigned short* Bs = smem + 4608;   // [256][SA]

    const int t = threadIdx.x;
    const int w = t >> 6, lane = t & 63;
    const int wm = w >> 2, wn = w & 3;          // 2m x 4n wave grid
    const int quad = lane >> 4, l16 = lane & 15;

    float4v acc[2][4];
#pragma unroll
    for (int mi = 0; mi < 2; mi++)
#pragma unroll
        for (int ni = 0; ni < 4; ni++) acc[mi][ni] = (float4v){0.f, 0.f, 0.f, 0.f};

    for (int ks = 0; ks < D_IN; ks += 64) {
        // A tile: 64 rows x 64 k fp32 -> bf16.  1024 float4 chunks / 512 thr = 2 each.
#pragma unroll
        for (int i = 0; i < 2; i++) {
            int s = t + i * 512;
            int row = s >> 4, c4 = (s & 15) << 2;
            int gr = m0 + row; if (gr >= NNODES) gr = NNODES - 1;
            float4 a = *(const float4*)(X + (size_t)gr * D_IN + ks + c4);
            ushort4 p;
            p.x = f32_to_bf16_rne(a.x); p.y = f32_to_bf16_rne(a.y);
            p.z = f32_to_bf16_rne(a.z); p.w = f32_to_bf16_rne(a.w);
            *(ushort4*)(As + row * SA + c4) = p;
        }
        // B tile: 256 n x 64 k bf16 from Wt.  2048 x 16B chunks / 512 thr = 4 each.
#pragma unroll
        for (int i = 0; i < 4; i++) {
            int s = t + i * 512;
            int n = s >> 3, seg = (s & 7) << 3;
            *(int4*)(Bs + n * SA + seg) =
                *(const int4*)(Wz + (size_t)n * 256 + ks + seg);
        }
        __syncthreads();
#pragma unroll
        for (int kk = 0; kk < 64; kk += 32) {
            short8 af[2], bf[4];
#pragma unroll
            for (int mi = 0; mi < 2; mi++)
                af[mi] = *(const short8*)(As + (wm * 32 + mi * 16 + l16) * SA + kk + quad * 8);
#pragma unroll
            for (int ni = 0; ni < 4; ni++)
                bf[ni] = *(const short8*)(Bs + (wn * 64 + ni * 16 + l16) * SA + kk + quad * 8);
#pragma unroll
            for (int mi = 0; mi < 2; mi++)
#pragma unroll
                for (int ni = 0; ni < 4; ni++)
                    acc[mi][ni] = __builtin_amdgcn_mfma_f32_16x16x32_bf16(
                        af[mi], bf[ni], acc[mi][ni], 0, 0, 0);
        }
        __syncthreads();
    }

    // Epilogue: bias fold (z==0 adds b1), bf16 pack, LDS-staged coalesced store.
    float bias[4];
#pragma unroll
    for (int ni = 0; ni < 4; ni++)
        bias[ni] = (zz == 0) ? b1[wn * 64 + ni * 16 + l16] : 0.f;

    unsigned short* Cs = smem;          // [64][136] = 17.4 KB, aliases staging
#pragma unroll
    for (int h = 0; h < 2; h++) {       // n-halves 0..127, 128..255
        if ((wn >> 1) == h) {
#pragma unroll
            for (int mi = 0; mi < 2; mi++)
#pragma unroll
                for (int ni = 0; ni < 4; ni++) {
                    int cl = (wn & 1) * 64 + ni * 16 + l16;
#pragma unroll
                    for (int r = 0; r < 4; r++) {
                        int row = wm * 32 + mi * 16 + quad * 4 + r;
                        Cs[row * 136 + cl] = f32_to_bf16_rne(acc[mi][ni][r] + bias[ni]);
                    }
                }
        }
        __syncthreads();
        // 64 rows x 128 cols = 1024 int4 chunks / 512 thr = 2 each
#pragma unroll
        for (int i = 0; i < 2; i++) {
            int s = t + i * 512;
            int row = s >> 4, seg = s & 15;
            int gr = m0 + row;
            if (gr < NNODES)
                *(int4*)(C + (size_t)gr * HID + h * 128 + seg * 8) =
                    *(const int4*)(Cs + row * 136 + seg * 8);
        }
        __syncthreads();
    }
}

// -------- Phase 2: out[e] = relu(U[s]+V[d]) . W2 + b2   (b1 folded into U) --------
// 16 edges per wave, half-wave pairing; one 1 KB wave-load per row gather.
__global__ __launch_bounds__(256) void edge_score_bf16(
    const unsigned short* __restrict__ U, const unsigned short* __restrict__ V,
    const float* __restrict__ W2, const float* __restrict__ b2,
    const int* __restrict__ epos, const int* __restrict__ eneg,
    float* __restrict__ out)
{
    const int w = threadIdx.x >> 6, lane = threadIdx.x & 63;
    const int half = lane >> 5, hl = lane & 31;
    const int ebase = blockIdx.x * 64 + w * 16;

    const int* ei = (ebase < NEDGE) ? epos : eneg;
    const int eb2 = (ebase < NEDGE) ? ebase : ebase - NEDGE;

    int sidx[8], didx[8];
#pragma unroll
    for (int p = 0; p < 8; p++) {
        int e = eb2 + 2 * p + half;
        sidx[p] = ei[e];
        didx[p] = ei[NEDGE + e];
    }
    ushort8 uu[8], vv[8];
#pragma unroll
    for (int p = 0; p < 8; p++)
        uu[p] = *(const ushort8*)(U + (size_t)sidx[p] * HID + hl * 8);
#pragma unroll
    for (int p = 0; p < 8; p++)
        vv[p] = *(const ushort8*)(V + (size_t)didx[p] * HID + hl * 8);

    float w2r[8];
    *(float4*)&w2r[0] = *(const float4*)(W2 + hl * 8);
    *(float4*)&w2r[4] = *(const float4*)(W2 + hl * 8 + 4);
    const float bb2 = b2[0];

#pragma unroll
    for (int p = 0; p < 8; p++) {
        float s = 0.f;
#pragma unroll
        for (int q = 0; q < 8; q++)
            s += fmaxf(bf16_to_f32(uu[p][q]) + bf16_to_f32(vv[p][q]), 0.f) * w2r[q];
#pragma unroll
        for (int off = 16; off; off >>= 1)
            s += __shfl_xor(s, off, 64);
        if (hl == 0) out[ebase + 2 * p + half] = s + bb2;
    }
}

// -------- Fallback (ws too small): direct per-edge MLP --------
__global__ __launch_bounds__(256) void edge_score_direct(
    const float* __restrict__ xs_, const float* __restrict__ xd_,
    const float* __restrict__ W1, const float* __restrict__ b1,
    const float* __restrict__ W2, const float* __restrict__ b2,
    const int* __restrict__ epos, const int* __restrict__ eneg,
    float* __restrict__ out)
{
    __shared__ float xrow[2 * D_IN];
    __shared__ float red[256];
    const int e = blockIdx.x;
    const int* ei = (e < NEDGE) ? epos : eneg;
    const int e2  = (e < NEDGE) ? e : e - NEDGE;
    const int s = ei[e2];
    const int d = ei[NEDGE + e2];
    const int t = threadIdx.x;

    xrow[t]        = xs_[(size_t)s * D_IN + t];
    xrow[D_IN + t] = xd_[(size_t)d * D_IN + t];
    __syncthreads();

    float acc = b1[t];
    for (int k = 0; k < 2 * D_IN; k++)
        acc += xrow[k] * W1[(size_t)k * HID + t];
    acc = fmaxf(acc, 0.f);
    red[t] = acc * W2[t];
    __syncthreads();
    for (int st = 128; st; st >>= 1) {
        if (t < st) red[t] += red[t + st];
        __syncthreads();
    }
    if (t == 0) out[e] = red[0] + b2[0];
}

extern "C" void kernel_launch(void* const* d_in, const int* in_sizes, int n_in,
                              void* d_out, int out_size, void* d_ws, size_t ws_size,
                              hipStream_t stream) {
    const float* x_src = (const float*)d_in[0];
    const float* x_dst = (const float*)d_in[1];
    const float* W1    = (const float*)d_in[2];
    const float* b1    = (const float*)d_in[3];
    const float* W2    = (const float*)d_in[4];
    const float* b2    = (const float*)d_in[5];
    const int*   epos  = (const int*)d_in[6];
    const int*   eneg  = (const int*)d_in[7];
    float* out = (float*)d_out;

    const size_t uv   = (size_t)NNODES * HID;
    const size_t need = (2 * uv + 2 * 256 * 256) * sizeof(unsigned short);
    if (ws_size >= need) {
        unsigned short* U  = (unsigned short*)d_ws;
        unsigned short* V  = U + uv;
        unsigned short* Wt = V + uv;
        convert_w<<<dim3(4, 4, 2), 256, 0, stream>>>(W1, Wt);
        dim3 g1((NNODES + 63) / 64, 1, 2);
        gemm_xw_mfma<<<g1, 512, 0, stream>>>(x_src, x_dst, Wt, b1, U, V);
        edge_score_bf16<<<(2 * NEDGE) / 64, 256, 0, stream>>>(U, V, W2, b2, epos, eneg, out);
    } else {
        edge_score_direct<<<2 * NEDGE, 256, 0, stream>>>(x_src, x_dst, W1, b1, W2, b2, epos, eneg, out);
    }
}